// Round 6
// baseline (679.071 us; speedup 1.0000x reference)
//
#include <hip/hip_runtime.h>
#include <math.h>

#define NG 100000
#define ND 50000
#define NTOT 150000
#define DIM 128
#define NE 800000
#define EPSN 1e-12f

#define NBT_D 391  // ceil(ND/128)
#define NBT_G 782  // ceil(NG/128)

#define NBK 586    // ceil(NTOT/256) buckets of 256 dst nodes
#define SCB 128    // scatter blocks
#define EPB 12500  // edges per scatter block = ceil(2*NE/SCB)

typedef __bf16 bf16x8 __attribute__((ext_vector_type(8)));
typedef float f32x4 __attribute__((ext_vector_type(4)));
typedef unsigned int uint32;

__device__ __forceinline__ ushort rne_bf16(float f) {
  uint32 u = __builtin_bit_cast(uint32, f);
  u += 0x7fffu + ((u >> 16) & 1u);
  return (ushort)(u >> 16);
}

// ---------------- bucketed CSR build (unchanged from R5 — proven cheap) ----------------

__global__ void zero_ints(int* __restrict__ p, int n) {
  int i = blockIdx.x * 256 + threadIdx.x;
  if (i < n) p[i] = 0;
}

__global__ void bucket_count(const int* __restrict__ dst_g2d, const int* __restrict__ dst_d2g,
                             int* __restrict__ bcnt) {
  __shared__ int h[NBK];
  for (int j = threadIdx.x; j < NBK; j += 256) h[j] = 0;
  __syncthreads();
  int stride = gridDim.x * 256;
  for (int i = blockIdx.x * 256 + threadIdx.x; i < 2 * NE; i += stride) {
    int d = (i < NE) ? dst_g2d[i] : ND + dst_d2g[i - NE];
    atomicAdd(&h[d >> 8], 1);
  }
  __syncthreads();
  for (int j = threadIdx.x; j < NBK; j += 256)
    if (h[j]) atomicAdd(&bcnt[j], h[j]);
}

__global__ void bucket_scan(const int* __restrict__ bcnt, int* __restrict__ bbase,
                            int* __restrict__ bcur) {
  __shared__ int s[1024];
  int t = threadIdx.x;
  s[t] = (t < NBK) ? bcnt[t] : 0;
  __syncthreads();
  for (int off = 1; off < 1024; off <<= 1) {
    int v = (t >= off) ? s[t - off] : 0;
    __syncthreads();
    s[t] += v;
    __syncthreads();
  }
  if (t < NBK) {
    int e = (t > 0) ? s[t - 1] : 0;
    bbase[t] = e;
    bcur[t] = e;
  }
  if (t == 0) bbase[NBK] = 2 * NE;
}

__global__ void bucket_scatter(const int* __restrict__ src_g2d, const int* __restrict__ dst_g2d,
                               const int* __restrict__ src_d2g, const int* __restrict__ dst_d2g,
                               int* __restrict__ bcur, int2* __restrict__ pairs) {
  __shared__ int h[NBK];
  __shared__ int base[NBK];
  int e0 = blockIdx.x * EPB;
  int e1 = e0 + EPB;
  if (e1 > 2 * NE) e1 = 2 * NE;
  for (int j = threadIdx.x; j < NBK; j += 256) h[j] = 0;
  __syncthreads();
  for (int i = e0 + threadIdx.x; i < e1; i += 256) {
    int d = (i < NE) ? dst_g2d[i] : ND + dst_d2g[i - NE];
    atomicAdd(&h[d >> 8], 1);
  }
  __syncthreads();
  for (int j = threadIdx.x; j < NBK; j += 256) {
    int c = h[j];
    base[j] = c ? atomicAdd(&bcur[j], c) : 0;
    h[j] = 0;
  }
  __syncthreads();
  for (int i = e0 + threadIdx.x; i < e1; i += 256) {
    int d, s;
    if (i < NE) {
      d = dst_g2d[i];
      s = src_g2d[i];
    } else {
      d = ND + dst_d2g[i - NE];
      s = src_d2g[i - NE];
    }
    int bkt = d >> 8;
    int p = base[bkt] + atomicAdd(&h[bkt], 1);
    pairs[p] = make_int2(d, s);
  }
}

__global__ void bucket_to_csr(const int* __restrict__ bbase, const int2* __restrict__ pairs,
                              int* __restrict__ off, int* __restrict__ csr) {
  __shared__ int cnt[256];
  __shared__ int ss[256];
  int b = blockIdx.x, t = threadIdx.x;
  int n0 = b << 8;
  int s0 = bbase[b], s1 = bbase[b + 1];
  cnt[t] = 0;
  __syncthreads();
  for (int i = s0 + t; i < s1; i += 256) atomicAdd(&cnt[pairs[i].x - n0], 1);
  __syncthreads();
  int x = cnt[t];
  ss[t] = x;
  __syncthreads();
  for (int o = 1; o < 256; o <<= 1) {
    int y = (t >= o) ? ss[t - o] : 0;
    __syncthreads();
    ss[t] += y;
    __syncthreads();
  }
  int abs0 = s0 + ss[t] - x;
  int node = n0 + t;
  if (node < NTOT) off[node] = abs0;
  if (node == NTOT - 1) off[NTOT] = 2 * NE;
  __syncthreads();
  cnt[t] = abs0;
  __syncthreads();
  for (int i = s0 + t; i < s1; i += 256) {
    int2 e = pairs[i];
    int p = atomicAdd(&cnt[e.x - n0], 1);
    csr[p] = e.y;
  }
}

// ---------------- fp32 -> bf16 table convert (RNE) ----------------

__global__ void to_bf16_all(const float* __restrict__ xg, const float* __restrict__ xd,
                            ushort* __restrict__ yg, ushort* __restrict__ yd) {
  int i = blockIdx.x * 256 + threadIdx.x;
  if (i >= NTOT * 16) return;
  const float* x;
  ushort* y;
  int j;
  if (i < NG * 16) {
    x = xg; y = yg; j = i;
  } else {
    x = xd; y = yd; j = i - NG * 16;
  }
  const float4* px = (const float4*)x;
  float4 a = px[2 * j], b = px[2 * j + 1];
  float v[8] = {a.x, a.y, a.z, a.w, b.x, b.y, b.z, b.w};
  uint32 u[4];
#pragma unroll
  for (int k = 0; k < 4; k++)
    u[k] = (uint32)rne_bf16(v[2 * k]) | ((uint32)rne_bf16(v[2 * k + 1]) << 16);
  ((int4*)y)[j] = make_int4((int)u[0], (int)u[1], (int)u[2], (int)u[3]);
}

// ---------------- W pre-split ----------------

__global__ void split_w(const float* __restrict__ Wl, const float* __restrict__ Wr,
                        ushort* __restrict__ WlH, ushort* __restrict__ WlL,
                        ushort* __restrict__ WrH, ushort* __restrict__ WrL) {
  int i = blockIdx.x * 256 + threadIdx.x;
  if (i >= 4 * 128 * 128) return;
  {
    float a = Wl[i];
    uint32 u = __builtin_bit_cast(uint32, a);
    float hf = __builtin_bit_cast(float, u & 0xffff0000u);
    WlH[i] = (ushort)(u >> 16);
    WlL[i] = (ushort)(__builtin_bit_cast(uint32, a - hf) >> 16);
  }
  {
    float a = Wr[i];
    uint32 u = __builtin_bit_cast(uint32, a);
    float hf = __builtin_bit_cast(float, u & 0xffff0000u);
    WrH[i] = (ushort)(u >> 16);
    WrL[i] = (ushort)(__builtin_bit_cast(uint32, a - hf) >> 16);
  }
}

// ---------------- fused gather-mean + MFMA SAGE update ----------------
// Block: 128 dst rows x 128 cols, 4 waves. Phase 1: gather-mean neighbors (bf16) straight
// into LDS sMean. Phase 2: C = mean*Wl^T (2 MFMA terms) + X*Wr^T (3 terms, split-bf16 X).
// Epilogue: +bias, (relu), row l2-norm, skip-add X, coalesced stores via LDS tile.

__device__ __forceinline__ void acc8(float* a, int4 u) {
  uint32 w;
  w = (uint32)u.x;
  a[0] += __builtin_bit_cast(float, w << 16);
  a[1] += __builtin_bit_cast(float, w & 0xffff0000u);
  w = (uint32)u.y;
  a[2] += __builtin_bit_cast(float, w << 16);
  a[3] += __builtin_bit_cast(float, w & 0xffff0000u);
  w = (uint32)u.z;
  a[4] += __builtin_bit_cast(float, w << 16);
  a[5] += __builtin_bit_cast(float, w & 0xffff0000u);
  w = (uint32)u.w;
  a[6] += __builtin_bit_cast(float, w << 16);
  a[7] += __builtin_bit_cast(float, w & 0xffff0000u);
}

__launch_bounds__(256)
__global__ void sage_fused(const ushort* __restrict__ xg_bf, const ushort* __restrict__ xd_bf,
                           const int* __restrict__ off, const int* __restrict__ csr,
                           const float* __restrict__ xd, const float* __restrict__ xg,
                           const ushort* __restrict__ WlH, const ushort* __restrict__ WlL,
                           const ushort* __restrict__ WrH, const ushort* __restrict__ WrL,
                           const float* __restrict__ bias_all, float* __restrict__ outd,
                           float* __restrict__ outg, ushort* __restrict__ xbf_d,
                           ushort* __restrict__ xbf_g, int layer, int relu, int write_bf) {
  __shared__ __align__(16) ushort smem[40960];  // 80 KB
  // sMean: [ks(4)][row(128)][40]  -> ushorts [0, 20480)
  // sW:    [plane(2)][row(128)][40] -> [20480, 30720)
  // sX:    [plane(2)][row(128)][40] -> [30720, 40960)
  ushort* sMean = smem;
  ushort* sW = smem + 20480;
  ushort* sX = smem + 30720;

  int b = blockIdx.x;
  const float* X;
  const ushort* XSBF;  // gather source table (bf16) = other node type
  float* O;
  ushort* OBF;
  int n, set, r0g, cbase;
  if (b < NBT_D) {
    X = xd; XSBF = xg_bf; O = outd; OBF = xbf_d; n = ND; set = layer * 2;
    r0g = b * 128; cbase = 0;
  } else {
    X = xg; XSBF = xd_bf; O = outg; OBF = xbf_g; n = NG; set = layer * 2 + 1;
    r0g = (b - NBT_D) * 128; cbase = ND;
  }
  const ushort* WH[2] = {WlH + set * 16384, WrH + set * 16384};
  const ushort* WL[2] = {WlL + set * 16384, WrL + set * 16384};
  const float* bias = bias_all + set * 128;

  int tid = threadIdx.x;
  int wave = tid >> 6, lane = tid & 63;
  int m = lane & 15, q = lane >> 4;

  // ---- phase 1: gather-mean -> sMean. 4 nodes per wave in parallel (nsel=q),
  //      16 lanes x 16B cover one 256B bf16 row. fp32 accum, RNE bf16 out. ----
  {
    int nsel = q, l16 = m;
    const int4* xs = (const int4*)XSBF;
#pragma unroll 1
    for (int g = 0; g < 8; g++) {
      int r = wave * 32 + g * 4 + nsel;  // block-local row
      int rg = r0g + r;
      bool valid = rg < n;
      int u = cbase + (valid ? rg : 0);
      int e0 = valid ? off[u] : 0;
      int e1 = valid ? off[u + 1] : 0;
      float a[8] = {0.f, 0.f, 0.f, 0.f, 0.f, 0.f, 0.f, 0.f};
      int e = e0;
      for (; e + 1 < e1; e += 2) {
        int s0 = csr[e], s1 = csr[e + 1];
        int4 v0 = xs[(size_t)s0 * 16 + l16];
        int4 v1 = xs[(size_t)s1 * 16 + l16];
        acc8(a, v0);
        acc8(a, v1);
      }
      if (e < e1) acc8(a, xs[(size_t)csr[e] * 16 + l16]);
      if (valid) {
        int deg = e1 - e0;
        float inv = (deg > 0) ? 1.f / (float)deg : 0.f;
        uint32 u4[4];
#pragma unroll
        for (int j = 0; j < 4; j++)
          u4[j] = (uint32)rne_bf16(a[2 * j] * inv) |
                  ((uint32)rne_bf16(a[2 * j + 1] * inv) << 16);
        // col block l16*8..+7 -> chunk ks=l16>>2, piece (l16&3)
        *(int4*)&sMean[(l16 >> 2) * 5120 + r * 40 + (l16 & 3) * 8] =
            make_int4((int)u4[0], (int)u4[1], (int)u4[2], (int)u4[3]);
      }
    }
  }
  // (visibility of sMean across waves guaranteed by the barriers inside the GEMM loop)

  f32x4 acc[2][8];
#pragma unroll
  for (int mt = 0; mt < 2; mt++)
#pragma unroll
    for (int nt = 0; nt < 8; nt++) acc[mt][nt] = (f32x4)0.f;

  int arow0 = wave * 32 + m;
  int arow1 = arow0 + 16;

  // ---- phase 2: GEMM over K=128 in 32-chunks; ph0 A = sMean (already in LDS) ----
#pragma unroll
  for (int ph = 0; ph < 2; ph++) {
#pragma unroll
    for (int ks = 0; ks < 4; ks++) {
      int k0 = ks * 32;
      int4 wv[4];
#pragma unroll
      for (int i = 0; i < 4; i++) {
        int u = tid + i * 256;  // [plane][row(128)][piece(4)] of 16B
        int pl = u >> 9, idx = u & 511, wn = idx >> 2, wp = idx & 3;
        const ushort* base = pl ? WL[ph] : WH[ph];
        wv[i] = *(const int4*)&base[wn * 128 + k0 + wp * 8];
      }
      float4 xv[4];
      if (ph == 1) {
#pragma unroll
        for (int i = 0; i < 4; i++) {
          int u = tid + i * 256;  // [row(128)][piece(8)] of 16B fp32
          int xn = u >> 3, xp = u & 7;
          int rg = r0g + xn;
          if (rg >= n) rg = n - 1;
          xv[i] = *(const float4*)&X[(size_t)rg * DIM + k0 + xp * 4];
        }
      }
      __syncthreads();  // prior chunk's LDS reads done (and, at ph0/ks0, gather complete)
#pragma unroll
      for (int i = 0; i < 4; i++) {
        int u = tid + i * 256;
        int pl = u >> 9, idx = u & 511, wn = idx >> 2, wp = idx & 3;
        *(int4*)&sW[pl * 5120 + wn * 40 + wp * 8] = wv[i];
      }
      if (ph == 1) {
#pragma unroll
        for (int i = 0; i < 4; i++) {
          int u = tid + i * 256;
          int xn = u >> 3, xp = u & 7;
          float v[4] = {xv[i].x, xv[i].y, xv[i].z, xv[i].w};
          ushort h[4], l[4];
#pragma unroll
          for (int j = 0; j < 4; j++) {
            uint32 uu = __builtin_bit_cast(uint32, v[j]);
            h[j] = (ushort)(uu >> 16);
            float hf = __builtin_bit_cast(float, uu & 0xffff0000u);
            l[j] = (ushort)(__builtin_bit_cast(uint32, v[j] - hf) >> 16);
          }
          int2 hp = make_int2((int)((uint32)h[0] | ((uint32)h[1] << 16)),
                              (int)((uint32)h[2] | ((uint32)h[3] << 16)));
          int2 lp = make_int2((int)((uint32)l[0] | ((uint32)l[1] << 16)),
                              (int)((uint32)l[2] | ((uint32)l[3] << 16)));
          *(int2*)&sX[xn * 40 + xp * 4] = hp;
          *(int2*)&sX[5120 + xn * 40 + xp * 4] = lp;
        }
      }
      __syncthreads();
      if (ph == 0) {
        bf16x8 a0 = __builtin_bit_cast(bf16x8, *(const int4*)&sMean[ks * 5120 + arow0 * 40 + q * 8]);
        bf16x8 a1 = __builtin_bit_cast(bf16x8, *(const int4*)&sMean[ks * 5120 + arow1 * 40 + q * 8]);
#pragma unroll
        for (int nt = 0; nt < 8; nt++) {
          int nn = nt * 16 + m;
          bf16x8 bh = __builtin_bit_cast(bf16x8, *(const int4*)&sW[nn * 40 + q * 8]);
          bf16x8 bl = __builtin_bit_cast(bf16x8, *(const int4*)&sW[5120 + nn * 40 + q * 8]);
          acc[0][nt] = __builtin_amdgcn_mfma_f32_16x16x32_bf16(a0, bh, acc[0][nt], 0, 0, 0);
          acc[1][nt] = __builtin_amdgcn_mfma_f32_16x16x32_bf16(a1, bh, acc[1][nt], 0, 0, 0);
          acc[0][nt] = __builtin_amdgcn_mfma_f32_16x16x32_bf16(a0, bl, acc[0][nt], 0, 0, 0);
          acc[1][nt] = __builtin_amdgcn_mfma_f32_16x16x32_bf16(a1, bl, acc[1][nt], 0, 0, 0);
        }
      } else {
        bf16x8 ah0 = __builtin_bit_cast(bf16x8, *(const int4*)&sX[arow0 * 40 + q * 8]);
        bf16x8 ah1 = __builtin_bit_cast(bf16x8, *(const int4*)&sX[arow1 * 40 + q * 8]);
        bf16x8 al0 = __builtin_bit_cast(bf16x8, *(const int4*)&sX[5120 + arow0 * 40 + q * 8]);
        bf16x8 al1 = __builtin_bit_cast(bf16x8, *(const int4*)&sX[5120 + arow1 * 40 + q * 8]);
#pragma unroll
        for (int nt = 0; nt < 8; nt++) {
          int nn = nt * 16 + m;
          bf16x8 bh = __builtin_bit_cast(bf16x8, *(const int4*)&sW[nn * 40 + q * 8]);
          bf16x8 bl = __builtin_bit_cast(bf16x8, *(const int4*)&sW[5120 + nn * 40 + q * 8]);
          acc[0][nt] = __builtin_amdgcn_mfma_f32_16x16x32_bf16(ah0, bh, acc[0][nt], 0, 0, 0);
          acc[1][nt] = __builtin_amdgcn_mfma_f32_16x16x32_bf16(ah1, bh, acc[1][nt], 0, 0, 0);
          acc[0][nt] = __builtin_amdgcn_mfma_f32_16x16x32_bf16(ah0, bl, acc[0][nt], 0, 0, 0);
          acc[1][nt] = __builtin_amdgcn_mfma_f32_16x16x32_bf16(ah1, bl, acc[1][nt], 0, 0, 0);
          acc[0][nt] = __builtin_amdgcn_mfma_f32_16x16x32_bf16(al0, bh, acc[0][nt], 0, 0, 0);
          acc[1][nt] = __builtin_amdgcn_mfma_f32_16x16x32_bf16(al1, bh, acc[1][nt], 0, 0, 0);
        }
      }
    }
  }
  __syncthreads();

  // ---- epilogue (reuses sW/sX region as per-wave fp32 tile) ----
  float bb[8];
#pragma unroll
  for (int nt = 0; nt < 8; nt++) bb[nt] = bias[nt * 16 + m];

  const int S = 132;
  float* wbuf = (float*)(smem + 20480) + wave * (16 * S);

  int half = lane >> 5;
  int c4 = (lane & 31) * 4;

#pragma unroll
  for (int mt = 0; mt < 2; mt++) {
#pragma unroll
    for (int reg = 0; reg < 4; reg++) {
      float h[8];
      float ss = 0.f;
#pragma unroll
      for (int nt = 0; nt < 8; nt++) {
        float v = acc[mt][nt][reg] + bb[nt];
        if (relu) v = fmaxf(v, 0.f);
        h[nt] = v;
        ss += v * v;
      }
      ss += __shfl_xor(ss, 1);
      ss += __shfl_xor(ss, 2);
      ss += __shfl_xor(ss, 4);
      ss += __shfl_xor(ss, 8);
      float inv = 1.f / fmaxf(sqrtf(ss), EPSN);
      int rrel = q * 4 + reg;
#pragma unroll
      for (int nt = 0; nt < 8; nt++) wbuf[rrel * S + nt * 16 + m] = h[nt] * inv;
    }
#pragma unroll
    for (int i = 0; i < 8; i++) {
      int rrel = i * 2 + half;
      int R = r0g + wave * 32 + mt * 16 + rrel;
      if (R < n) {
        f32x4 hv = *(const f32x4*)&wbuf[rrel * S + c4];
        float4 xr = *(const float4*)&X[(size_t)R * DIM + c4];
        float4 o;
        o.x = hv[0] + xr.x;
        o.y = hv[1] + xr.y;
        o.z = hv[2] + xr.z;
        o.w = hv[3] + xr.w;
        *(float4*)&O[(size_t)R * DIM + c4] = o;
        if (write_bf) {
          int2 pk = make_int2((int)((uint32)rne_bf16(o.x) | ((uint32)rne_bf16(o.y) << 16)),
                              (int)((uint32)rne_bf16(o.z) | ((uint32)rne_bf16(o.w) << 16)));
          *(int2*)&OBF[(size_t)R * DIM + c4] = pk;
        }
      }
    }
  }
}

// ---------------- launch ----------------

extern "C" void kernel_launch(void* const* d_in, const int* in_sizes, int n_in,
                              void* d_out, int out_size, void* d_ws, size_t ws_size,
                              hipStream_t stream) {
  const float* xg0 = (const float*)d_in[0];
  const float* xd0 = (const float*)d_in[1];
  const float* Wl = (const float*)d_in[2];
  const float* Wr = (const float*)d_in[3];
  const float* bs = (const float*)d_in[4];
  const int* src_g2d = (const int*)d_in[5];
  const int* dst_g2d = (const int*)d_in[6];
  const int* src_d2g = (const int*)d_in[7];
  const int* dst_d2g = (const int*)d_in[8];

  float* out_xg = (float*)d_out;
  float* out_xd = (float*)d_out + (size_t)NG * DIM;

  char* p = (char*)d_ws;
  auto alloc = [&](size_t bytes) -> char* {
    char* q = p;
    p += (bytes + 255) & ~(size_t)255;
    return q;
  };
  int* off = (int*)alloc((NTOT + 1) * 4);
  int* csr = (int*)alloc((size_t)2 * NE * 4);
  int* bcnt = (int*)alloc(NBK * 4);
  int* bbase = (int*)alloc((NBK + 1) * 4);
  int* bcur = (int*)alloc(NBK * 4);
  int2* pairs = (int2*)alloc((size_t)2 * NE * 8);
  ushort* xg_bf = (ushort*)alloc((size_t)NG * DIM * 2);
  ushort* xd_bf = (ushort*)alloc((size_t)ND * DIM * 2);
  ushort* WlH = (ushort*)alloc((size_t)4 * 128 * 128 * 2);
  ushort* WlL = (ushort*)alloc((size_t)4 * 128 * 128 * 2);
  ushort* WrH = (ushort*)alloc((size_t)4 * 128 * 128 * 2);
  ushort* WrL = (ushort*)alloc((size_t)4 * 128 * 128 * 2);

  const int TB = 256;

  split_w<<<256, TB, 0, stream>>>(Wl, Wr, WlH, WlL, WrH, WrL);
  to_bf16_all<<<(NTOT * 16 + TB - 1) / TB, TB, 0, stream>>>(xg0, xd0, xg_bf, xd_bf);

  // bucketed CSR build
  zero_ints<<<(NBK + TB - 1) / TB, TB, 0, stream>>>(bcnt, NBK);
  bucket_count<<<256, TB, 0, stream>>>(dst_g2d, dst_d2g, bcnt);
  bucket_scan<<<1, 1024, 0, stream>>>(bcnt, bbase, bcur);
  bucket_scatter<<<SCB, TB, 0, stream>>>(src_g2d, dst_g2d, src_d2g, dst_d2g, bcur, pairs);
  bucket_to_csr<<<NBK, TB, 0, stream>>>(bbase, pairs, off, csr);

  int sageBlocks = NBT_D + NBT_G;  // 1173

  // layer 0 (relu); also emits bf16 copy of out for layer-1 gather
  sage_fused<<<sageBlocks, TB, 0, stream>>>(xg_bf, xd_bf, off, csr, xd0, xg0, WlH, WlL, WrH,
                                            WrL, bs, out_xd, out_xg, xd_bf, xg_bf, 0, 1, 1);

  // layer 1 (no relu), in-place on d_out (gather uses bf16 tables written by layer 0)
  sage_fused<<<sageBlocks, TB, 0, stream>>>(xg_bf, xd_bf, off, csr, out_xd, out_xg, WlH, WlL,
                                            WrH, WrL, bs, out_xd, out_xg, xd_bf, xg_bf, 1, 0,
                                            0);
}